// Round 1
// baseline (201.880 us; speedup 1.0000x reference)
//
#include <hip/hip_runtime.h>
#include <stdint.h>

// BertSelfAttentionWithRelation  B=4 L=512 H=12 D=64 HIDDEN=768
// Round 0: correctness-first full pipeline.
//   ws layout (bytes):
//     hb   bf16 hidden        [2048][768]           3,145,728
//     wt   bf16 W^T concat    [2304][768]           3,538,944
//     qbf  bf16 q [B][H][L][D]                      3,145,728
//     kbf  bf16 k [B][H][L][D]                      3,145,728
//     vbt  bf16 v^T [B][H][D][L]                    3,145,728
//     S    f32 content scores [B][H][L][L]         50,331,648
//     pbf  bf16 probs [B][H][L][L]                 25,165,824
//     crel f32 relation-ctx   [B][L][768]           6,291,456
//   total ~97.9 MB

typedef __attribute__((ext_vector_type(8))) short bf16x8;
typedef __attribute__((ext_vector_type(4))) float f32x4;
typedef __attribute__((ext_vector_type(4))) unsigned int u32x4;

__device__ __forceinline__ unsigned short f2bf(float f) {
  union { float f; unsigned int u; } v; v.f = f;
  unsigned int r = v.u + 0x7fffu + ((v.u >> 16) & 1u);
  return (unsigned short)(r >> 16);
}
__device__ __forceinline__ float bf2f(unsigned short s) {
  union { unsigned int u; float f; } v; v.u = ((unsigned int)s) << 16;
  return v.f;
}

// ---------------- K0a: hidden fp32 -> bf16 ----------------
__global__ void k_cvt_hidden(const float* __restrict__ x, unsigned short* __restrict__ y) {
  int i = blockIdx.x * 256 + threadIdx.x;        // 1536*256 = 393216 float4s exactly
  float4 v = reinterpret_cast<const float4*>(x)[i];
  ushort4 o;
  o.x = f2bf(v.x); o.y = f2bf(v.y); o.z = f2bf(v.z); o.w = f2bf(v.w);
  reinterpret_cast<ushort4*>(y)[i] = o;
}

// ---------------- K0b: W -> W^T concat bf16  wt[n][k] = W[k][n] ----------------
__global__ void k_transp_w(const float* __restrict__ Wq, const float* __restrict__ Wk,
                           const float* __restrict__ Wv, unsigned short* __restrict__ wt) {
  __shared__ float t[64][65];
  const int kt = blockIdx.x, nt = blockIdx.y, wsel = blockIdx.z;
  const float* W = wsel == 0 ? Wq : (wsel == 1 ? Wk : Wv);
  const int lx = threadIdx.x & 63, ly = threadIdx.x >> 6;
  for (int i = 0; i < 64; i += 4)
    t[ly + i][lx] = W[(size_t)(kt * 64 + ly + i) * 768 + nt * 64 + lx];
  __syncthreads();
  for (int i = 0; i < 64; i += 4) {
    int r = ly + i;
    wt[((size_t)wsel * 768 + nt * 64 + r) * 768 + kt * 64 + lx] = f2bf(t[lx][r]);
  }
}

// ---------------- K1: fused QKV GEMM (bf16 MFMA) ----------------
// C-equivalent outputs written directly as bf16 side-buffers.
__global__ __launch_bounds__(256) void k_qkv_gemm(
    const unsigned short* __restrict__ A,   // [2048][768] bf16
    const unsigned short* __restrict__ Bt,  // [2304][768] bf16 (row n, col k)
    const float* __restrict__ bq, const float* __restrict__ bk, const float* __restrict__ bv,
    unsigned short* __restrict__ qbf,       // [B][H][L][D]
    unsigned short* __restrict__ kbf,       // [B][H][L][D]
    unsigned short* __restrict__ vbt) {     // [B][H][D][L]
  __shared__ __align__(16) unsigned short lA[64 * 64];
  __shared__ __align__(16) unsigned short lB[64 * 64];
  const int tid = threadIdx.x, lane = tid & 63, w = tid >> 6;
  const int m0 = blockIdx.x * 64, n0 = blockIdx.y * 64;
  const int wm = (w >> 1) * 32, wn = (w & 1) * 32;
  f32x4 acc[2][2] = {};

  for (int kt = 0; kt < 12; ++kt) {
    __syncthreads();
#pragma unroll
    for (int i = 0; i < 2; ++i) {
      int e16 = i * 256 + tid;          // 16B unit, 0..511 (64 rows x 128B)
      int row = e16 >> 3;
      int kb = (e16 & 7) * 16;
      int dst = row * 128 + (kb ^ ((row & 7) << 4));   // XOR swizzle, bank-conflict-free frag reads
      u32x4 va = *(const u32x4*)((const char*)A + (size_t)(m0 + row) * 1536 + kt * 128 + kb);
      *(u32x4*)((char*)lA + dst) = va;
      u32x4 vb = *(const u32x4*)((const char*)Bt + (size_t)(n0 + row) * 1536 + kt * 128 + kb);
      *(u32x4*)((char*)lB + dst) = vb;
    }
    __syncthreads();
#pragma unroll
    for (int ks = 0; ks < 2; ++ks) {
      bf16x8 fa[2], fb[2];
      const int kbyte = (ks * 32 + (lane >> 4) * 8) * 2;
#pragma unroll
      for (int mi = 0; mi < 2; ++mi) {
        int row = wm + mi * 16 + (lane & 15);
        fa[mi] = *(const bf16x8*)((const char*)lA + row * 128 + (kbyte ^ ((row & 7) << 4)));
      }
#pragma unroll
      for (int ni = 0; ni < 2; ++ni) {
        int row = wn + ni * 16 + (lane & 15);
        fb[ni] = *(const bf16x8*)((const char*)lB + row * 128 + (kbyte ^ ((row & 7) << 4)));
      }
#pragma unroll
      for (int mi = 0; mi < 2; ++mi)
#pragma unroll
        for (int ni = 0; ni < 2; ++ni)
          acc[mi][ni] = __builtin_amdgcn_mfma_f32_16x16x32_bf16(fa[mi], fb[ni], acc[mi][ni], 0, 0, 0);
    }
  }
  // epilogue: C/D layout col=lane&15, row=(lane>>4)*4+r  [m89-verified]
#pragma unroll
  for (int mi = 0; mi < 2; ++mi)
#pragma unroll
    for (int ni = 0; ni < 2; ++ni) {
      int gn = n0 + wn + ni * 16 + (lane & 15);
      float bias = (gn < 768) ? bq[gn] : (gn < 1536 ? bk[gn - 768] : bv[gn - 1536]);
#pragma unroll
      for (int r = 0; r < 4; ++r) {
        int gm = m0 + wm + mi * 16 + ((lane >> 4) << 2) + r;
        float val = acc[mi][ni][r] + bias;
        int b = gm >> 9, l = gm & 511;
        int d = gn & 63;
        if (gn < 768) {
          int h = gn >> 6;
          qbf[(((size_t)(b * 12 + h)) * 512 + l) * 64 + d] = f2bf(val);
        } else if (gn < 1536) {
          int h = (gn - 768) >> 6;
          kbf[(((size_t)(b * 12 + h)) * 512 + l) * 64 + d] = f2bf(val);
        } else {
          int h = (gn - 1536) >> 6;
          vbt[(((size_t)(b * 12 + h)) * 64 + d) * 512 + l] = f2bf(val);
        }
      }
    }
}

// ---------------- K2a: content scores S = q.k^T per (b,h) via MFMA ----------------
__global__ __launch_bounds__(256) void k_scores(
    const unsigned short* __restrict__ qbf, const unsigned short* __restrict__ kbf,
    float* __restrict__ S) {
  __shared__ __align__(16) unsigned short lQ[64 * 64];
  __shared__ __align__(16) unsigned short lK[64 * 64];
  const int tid = threadIdx.x, lane = tid & 63, w = tid >> 6;
  const int mt = blockIdx.x, lt = blockIdx.y, bh = blockIdx.z;
  const int wm = (w >> 1) * 32, wn = (w & 1) * 32;
  f32x4 acc[2][2] = {};
#pragma unroll
  for (int i = 0; i < 2; ++i) {
    int e16 = i * 256 + tid;
    int row = e16 >> 3;
    int kb = (e16 & 7) * 16;
    int dst = row * 128 + (kb ^ ((row & 7) << 4));
    u32x4 vq = *(const u32x4*)((const char*)qbf + ((size_t)bh * 512 + lt * 64 + row) * 128 + kb);
    *(u32x4*)((char*)lQ + dst) = vq;
    u32x4 vk = *(const u32x4*)((const char*)kbf + ((size_t)bh * 512 + mt * 64 + row) * 128 + kb);
    *(u32x4*)((char*)lK + dst) = vk;
  }
  __syncthreads();
#pragma unroll
  for (int ks = 0; ks < 2; ++ks) {
    bf16x8 fa[2], fb[2];
    const int kbyte = (ks * 32 + (lane >> 4) * 8) * 2;
#pragma unroll
    for (int mi = 0; mi < 2; ++mi) {
      int row = wm + mi * 16 + (lane & 15);
      fa[mi] = *(const bf16x8*)((const char*)lQ + row * 128 + (kbyte ^ ((row & 7) << 4)));
    }
#pragma unroll
    for (int ni = 0; ni < 2; ++ni) {
      int row = wn + ni * 16 + (lane & 15);
      fb[ni] = *(const bf16x8*)((const char*)lK + row * 128 + (kbyte ^ ((row & 7) << 4)));
    }
#pragma unroll
    for (int mi = 0; mi < 2; ++mi)
#pragma unroll
      for (int ni = 0; ni < 2; ++ni)
        acc[mi][ni] = __builtin_amdgcn_mfma_f32_16x16x32_bf16(fa[mi], fb[ni], acc[mi][ni], 0, 0, 0);
  }
#pragma unroll
  for (int mi = 0; mi < 2; ++mi)
#pragma unroll
    for (int ni = 0; ni < 2; ++ni) {
      int gm = mt * 64 + wn + ni * 16 + (lane & 15);
#pragma unroll
      for (int r = 0; r < 4; ++r) {
        int gl = lt * 64 + wm + mi * 16 + ((lane >> 4) << 2) + r;
        S[(size_t)bh * 262144 + (size_t)gl * 512 + gm] = acc[mi][ni][r];
      }
    }
}

// ---------------- K2b: relation-K scores + softmax + relation-V, per (b,l) ----------------
__global__ __launch_bounds__(256) void k_attn_mid(
    const unsigned short* __restrict__ qbf,
    const float* __restrict__ relk,   // [B][L][L][D]  (b, l, r, d)
    const float* __restrict__ relv,   // [B][L][L][D]  indexed (b, r, l, d)
    const float* __restrict__ S,
    unsigned short* __restrict__ pbf,
    float* __restrict__ crel) {       // [B][L][768]
  __shared__ __align__(16) float qs[12 * 64];
  __shared__ __align__(16) float ps[12 * 512];
  __shared__ __align__(16) float rk[64 * 64];   // swizzled relk tile; reused for reduction
  const int tid = threadIdx.x, lane = tid & 63, w = tid >> 6;
  const int bl = blockIdx.x;
  const int b = bl >> 9, l = bl & 511;

  for (int i = tid; i < 768; i += 256) {
    int h = i >> 6, d = i & 63;
    qs[i] = bf2f(qbf[(((size_t)(b * 12 + h)) * 512 + l) * 64 + d]);
  }

  float acc[3][8];
#pragma unroll
  for (int hh = 0; hh < 3; ++hh)
#pragma unroll
    for (int j = 0; j < 8; ++j) acc[hh][j] = 0.f;

  const char* relk_base = (const char*)relk + (size_t)bl * 131072;
  for (int t8 = 0; t8 < 8; ++t8) {
    __syncthreads();
#pragma unroll
    for (int i = 0; i < 4; ++i) {
      int e16 = i * 256 + tid;      // 0..1023 (64 rows x 256B)
      int row = e16 >> 4;
      int kb = (e16 & 15) * 16;
      int dst = row * 256 + (kb ^ ((row & 7) << 4));
      u32x4 v = *(const u32x4*)(relk_base + (size_t)t8 * 16384 + (size_t)e16 * 16);
      *(u32x4*)((char*)rk + dst) = v;
    }
    __syncthreads();
    // lane owns m = t8*64+lane; wave owns heads w*3..w*3+2
#pragma unroll 4
    for (int dc = 0; dc < 16; ++dc) {
      f32x4 rv = *(const f32x4*)((const char*)rk + lane * 256 + ((dc * 16) ^ ((lane & 7) << 4)));
#pragma unroll
      for (int hh = 0; hh < 3; ++hh) {
        f32x4 q4 = *(const f32x4*)&qs[(w * 3 + hh) * 64 + dc * 4];
        acc[hh][t8] += rv.x * q4.x + rv.y * q4.y + rv.z * q4.z + rv.w * q4.w;
      }
    }
  }

  // content add, scale, softmax (wave-parallel: row h lives on one wave)
#pragma unroll
  for (int hh = 0; hh < 3; ++hh) {
    int h = w * 3 + hh;
    size_t srow = (((size_t)(b * 12 + h)) * 512 + l) * 512;
    float mx = -1e30f;
#pragma unroll
    for (int j = 0; j < 8; ++j) {
      float s = (acc[hh][j] + S[srow + j * 64 + lane]) * 0.125f;
      acc[hh][j] = s;
      mx = fmaxf(mx, s);
    }
#pragma unroll
    for (int off = 32; off; off >>= 1) mx = fmaxf(mx, __shfl_xor(mx, off));
    float sm = 0.f;
#pragma unroll
    for (int j = 0; j < 8; ++j) { acc[hh][j] = __expf(acc[hh][j] - mx); sm += acc[hh][j]; }
#pragma unroll
    for (int off = 32; off; off >>= 1) sm += __shfl_xor(sm, off);
    float inv = 1.f / sm;
#pragma unroll
    for (int j = 0; j < 8; ++j) {
      float pv = acc[hh][j] * inv;
      ps[h * 512 + j * 64 + lane] = pv;
      pbf[srow + j * 64 + lane] = f2bf(pv);
    }
  }
  __syncthreads();

  // relation-V: wave w handles r in [w*128, w*128+128), all 12 heads, lane -> d
  float cacc[12];
#pragma unroll
  for (int h = 0; h < 12; ++h) cacc[h] = 0.f;
  for (int rc = 0; rc < 32; ++rc) {
    int r0 = w * 128 + rc * 4;
    float v0 = relv[(((size_t)(b * 512 + r0 + 0)) * 512 + l) * 64 + lane];
    float v1 = relv[(((size_t)(b * 512 + r0 + 1)) * 512 + l) * 64 + lane];
    float v2 = relv[(((size_t)(b * 512 + r0 + 2)) * 512 + l) * 64 + lane];
    float v3 = relv[(((size_t)(b * 512 + r0 + 3)) * 512 + l) * 64 + lane];
#pragma unroll
    for (int h = 0; h < 12; ++h) {
      f32x4 p4 = *(const f32x4*)&ps[h * 512 + r0];
      cacc[h] += p4.x * v0 + p4.y * v1 + p4.z * v2 + p4.w * v3;
    }
  }
  __syncthreads();
  float* red = rk;   // 4*12*64 = 3072 floats <= 4096
#pragma unroll
  for (int h = 0; h < 12; ++h) red[(w * 12 + h) * 64 + lane] = cacc[h];
  __syncthreads();
  for (int i = tid; i < 768; i += 256) {
    int h = i >> 6, d = i & 63;
    float s = red[h * 64 + d] + red[(12 + h) * 64 + d] + red[(24 + h) * 64 + d] + red[(36 + h) * 64 + d];
    crel[(size_t)bl * 768 + i] = s;
  }
}

// ---------------- K3: ctx = P@V per (b,h) via MFMA, + crel, write out ----------------
__global__ __launch_bounds__(256) void k_pv(
    const unsigned short* __restrict__ pbf,   // [B][H][L][M]
    const unsigned short* __restrict__ vbt,   // [B][H][D][M]
    const float* __restrict__ crel,
    float* __restrict__ out) {
  __shared__ __align__(16) unsigned short lP[64 * 64];
  __shared__ __align__(16) unsigned short lV[64 * 64];
  const int tid = threadIdx.x, lane = tid & 63, w = tid >> 6;
  const int lt = blockIdx.x, bh = blockIdx.y;
  const int b = bh / 12, h = bh % 12;
  const int wm = (w >> 1) * 32, wn = (w & 1) * 32;
  f32x4 acc[2][2] = {};
  const char* pbase = (const char*)pbf + ((size_t)bh * 512 + lt * 64) * 1024;
  const char* vbase = (const char*)vbt + (size_t)bh * 64 * 1024;
  for (int kt = 0; kt < 8; ++kt) {
    __syncthreads();
#pragma unroll
    for (int i = 0; i < 2; ++i) {
      int e16 = i * 256 + tid;
      int row = e16 >> 3;
      int kb = (e16 & 7) * 16;
      int dst = row * 128 + (kb ^ ((row & 7) << 4));
      u32x4 vp = *(const u32x4*)(pbase + (size_t)row * 1024 + kt * 128 + kb);
      *(u32x4*)((char*)lP + dst) = vp;
      u32x4 vv = *(const u32x4*)(vbase + (size_t)row * 1024 + kt * 128 + kb);
      *(u32x4*)((char*)lV + dst) = vv;
    }
    __syncthreads();
#pragma unroll
    for (int ks = 0; ks < 2; ++ks) {
      bf16x8 fa[2], fb[2];
      const int kbyte = (ks * 32 + (lane >> 4) * 8) * 2;
#pragma unroll
      for (int mi = 0; mi < 2; ++mi) {
        int row = wm + mi * 16 + (lane & 15);
        fa[mi] = *(const bf16x8*)((const char*)lP + row * 128 + (kbyte ^ ((row & 7) << 4)));
      }
#pragma unroll
      for (int ni = 0; ni < 2; ++ni) {
        int row = wn + ni * 16 + (lane & 15);
        fb[ni] = *(const bf16x8*)((const char*)lV + row * 128 + (kbyte ^ ((row & 7) << 4)));
      }
#pragma unroll
      for (int mi = 0; mi < 2; ++mi)
#pragma unroll
        for (int ni = 0; ni < 2; ++ni)
          acc[mi][ni] = __builtin_amdgcn_mfma_f32_16x16x32_bf16(fa[mi], fb[ni], acc[mi][ni], 0, 0, 0);
    }
  }
#pragma unroll
  for (int mi = 0; mi < 2; ++mi)
#pragma unroll
    for (int ni = 0; ni < 2; ++ni) {
      int gd = wn + ni * 16 + (lane & 15);
#pragma unroll
      for (int r = 0; r < 4; ++r) {
        int gl = lt * 64 + wm + mi * 16 + ((lane >> 4) << 2) + r;
        size_t o = ((size_t)b * 512 + gl) * 768 + h * 64 + gd;
        out[o] = acc[mi][ni][r] + crel[o];
      }
    }
}

extern "C" void kernel_launch(void* const* d_in, const int* in_sizes, int n_in,
                              void* d_out, int out_size, void* d_ws, size_t ws_size,
                              hipStream_t stream) {
  (void)in_sizes; (void)n_in; (void)out_size; (void)ws_size;
  const float* hidden = (const float*)d_in[0];
  const float* relk   = (const float*)d_in[1];
  const float* relv   = (const float*)d_in[2];
  const float* Wq     = (const float*)d_in[3];
  const float* bq     = (const float*)d_in[4];
  const float* Wk     = (const float*)d_in[5];
  const float* bk     = (const float*)d_in[6];
  const float* Wv     = (const float*)d_in[7];
  const float* bv     = (const float*)d_in[8];
  float* out = (float*)d_out;
  char* ws = (char*)d_ws;

  unsigned short* hb  = (unsigned short*)(ws);
  unsigned short* wt  = (unsigned short*)(ws + 3145728);
  unsigned short* qbf = (unsigned short*)(ws + 6684672);
  unsigned short* kbf = (unsigned short*)(ws + 9830400);
  unsigned short* vbt = (unsigned short*)(ws + 12976128);
  float*          S   = (float*)(ws + 16121856);
  unsigned short* pbf = (unsigned short*)(ws + 66453504);
  float*          cr  = (float*)(ws + 91619328);
  // end: 97,910,784 bytes

  k_cvt_hidden<<<1536, 256, 0, stream>>>(hidden, hb);
  k_transp_w<<<dim3(12, 12, 3), 256, 0, stream>>>(Wq, Wk, Wv, wt);
  k_qkv_gemm<<<dim3(32, 36), 256, 0, stream>>>(hb, wt, bq, bk, bv, qbf, kbf, vbt);
  k_scores<<<dim3(8, 8, 48), 256, 0, stream>>>(qbf, kbf, S);
  k_attn_mid<<<2048, 256, 0, stream>>>(qbf, relk, relv, S, pbf, cr);
  k_pv<<<dim3(8, 48), 256, 0, stream>>>(pbf, vbt, cr, out);
}